// Round 11
// baseline (9060.197 us; speedup 1.0000x reference)
//
#include <hip/hip_runtime.h>

#define Bsz 64
#define Tn 256
#define Hn 512
#define Ln 4
#define Gn 2048
#define TTn 320
#define NBLK 256
#define NTHR 512
#define HB (Hn * Bsz)
#define LHB (Ln * HB)
#define NPH_W (Tn + Ln - 1)   // 259 diagonal warmup phases

typedef float f32x4 __attribute__((ext_vector_type(4)));

// ---- LDS layout (float offsets) ----
#define OFF_WHH  0                                // [4][8][512]
#define OFF_WIH  (OFF_WHH + Ln * 8 * Hn)          // [3][8][512]
#define OFF_PART (OFF_WIH + (Ln - 1) * 8 * Hn)    // warmup [4][2][8][64] / future [8][8][64]
#define OFF_GSUM (OFF_PART + 8 * 8 * Bsz)         // warmup [4][8][64] / future [8][64]
#define OFF_BS   (OFF_GSUM + Ln * 8 * Bsz)        // [4][8]
#define OFF_W0   (OFF_BS + Ln * 8)                // [8]
#define OFF_WLIN (OFF_W0 + 8)                     // [512]
#define OFF_RP   (OFF_WLIN + Hn)                  // [8][64]
#define OFF_XS   (OFF_RP + 8 * Bsz)               // [64]
#define OFF_C    (OFF_XS + Bsz)                   // [4][2][64]
#define SMEM_FLOATS (OFF_C + Ln * 2 * Bsz)
#define SMEM_BYTES (SMEM_FLOATS * 4)              // ~142.4 KB

// ---- workspace (u32; zeroed by hipMemsetAsync each launch) ----
#define WS_BCOUNT   0                    // [16] blocks per XCD (discovery)
#define WS_ARRIVE   16                   // [16][32] per-XCD arrival ctrs (spaced)
#define WS_INVD     (16 + 16 * 32)       // [16][32] per-XCD inv-done ctrs (spaced)
#define WS_MASTER   (16 + 32 * 32)
#define WS_FLAG     (WS_MASTER + 32)
#define WS_BOOT     (WS_FLAG + 32)
#define WS_BOOTFLAG (WS_BOOT + 32)
#define WS_U32S     (WS_BOOTFLAG + 32)

__device__ float g_h[2 * LHB];        // h double-buffered by phase/t parity
__device__ float g_hist[Tn * HB];     // h3 history for batched warmup readout
__device__ float g_p[Bsz * NBLK];     // distributed readout partials [b][block]
__device__ float g_xsg[Bsz];          // x seed for t=256

__device__ __forceinline__ float sigm(float x) { return 1.0f / (1.0f + expf(-x)); }

__device__ __forceinline__ void fma4v(f32x4& a, const f32x4 h, const float w) {
    a.x = fmaf(h.x, w, a.x); a.y = fmaf(h.y, w, a.y);
    a.z = fmaf(h.z, w, a.z); a.w = fmaf(h.w, w, a.w);
}

// write-through store toward the L3 coherence point (R9/R10-proven path).
#define GSTF(ptr, val) \
    asm volatile("global_store_dword %0, %1, off sc0 sc1" \
                 :: "v"(ptr), "v"(val) : "memory")
#define VMWAIT() asm volatile("s_waitcnt vmcnt(0)" ::: "memory")
// L1-only invalidate of THIS CU's vector cache (sc1 would add the L2 walk).
#define L1INV() asm volatile("buffer_inv" ::: "memory")

__device__ __forceinline__ uint32_t rmw_add(uint32_t* p, uint32_t v) {
    return __hip_atomic_fetch_add(p, v, __ATOMIC_RELAXED, __HIP_MEMORY_SCOPE_AGENT);
}
__device__ __forceinline__ uint32_t ald(const uint32_t* p) {
    return __hip_atomic_load(p, __ATOMIC_RELAXED, __HIP_MEMORY_SCOPE_AGENT);
}
__device__ __forceinline__ uint32_t xcc_id() {
    uint32_t x;
    asm("s_getreg_b32 %0, hwreg(HW_REG_XCC_ID)" : "=s"(x));
    return x & 15u;
}

// Bootstrap barrier (once): per-block release+acquire, counts blocks per XCD.
__device__ __forceinline__ void boot_bar(uint32_t* wsb, int tid) {
    VMWAIT();
    __syncthreads();
    if (tid == 0) {
        __builtin_amdgcn_fence(__ATOMIC_RELEASE, "agent");
        uint32_t old = rmw_add(wsb + WS_BOOT, 1u);
        if (old == NBLK - 1u) rmw_add(wsb + WS_BOOTFLAG, 1u);
        while (ald(wsb + WS_BOOTFLAG) < 1u) __builtin_amdgcn_s_sleep(2);
        __builtin_amdgcn_fence(__ATOMIC_ACQUIRE, "agent");
    }
    __syncthreads();
    asm volatile("" ::: "memory");
}

// Grid barrier v11: NO release fence (all cross-block data stores are
// sc0 sc1 write-through and drained via vmcnt(0) before arrival — the wbl2
// protected nothing). Leader-only L2 ACQUIRE (one inv/XCD) after the gate;
// peers poll invdone then L1-only invalidate (R10-proven split).
__device__ __forceinline__ void gbar(uint32_t* wsb, int tid, uint32_t x,
                                     uint32_t cnt_x, uint32_t& e) {
    ++e;
    VMWAIT();          // all write-through stores committed before arriving
    __syncthreads();
    if (tid == 0) {
        uint32_t old = rmw_add(wsb + WS_ARRIVE + x * 32, 1u);
        if (old == e * cnt_x - 1u) {            // leader: last arriver on XCD
            uint32_t m = rmw_add(wsb + WS_MASTER, cnt_x);
            if (m + cnt_x == e * (uint32_t)NBLK)
                rmw_add(wsb + WS_FLAG, 1u);     // last XCD: open the gate
            while (ald(wsb + WS_FLAG) < e) __builtin_amdgcn_s_sleep(1);
            __builtin_amdgcn_fence(__ATOMIC_ACQUIRE, "agent");  // inv L1+L2
            rmw_add(wsb + WS_INVD + x * 32, 1u);
        } else {                                // peer: wait for L2 clean,
            while (ald(wsb + WS_INVD + x * 32) < e) __builtin_amdgcn_s_sleep(1);
            L1INV();                            // then invalidate own L1
            VMWAIT();
        }
    }
    __syncthreads();
    asm volatile("" ::: "memory");
}

// Future-section partial GEMM: thread's 16-k chunk, plain loads.
__device__ __forceinline__ void gemm16(const float* __restrict__ w,     // LDS [8][512]
                                       const float* __restrict__ hbase, // global [512][64]
                                       int k0, int b4, f32x4* acc) {
#pragma unroll
    for (int c = 0; c < 4; ++c) {
        const int k = k0 + c * 4;
        const float* hp = hbase + (size_t)k * Bsz + b4;
        const f32x4 h0 = *(const f32x4*)(hp);
        const f32x4 h1 = *(const f32x4*)(hp + Bsz);
        const f32x4 h2 = *(const f32x4*)(hp + 2 * Bsz);
        const f32x4 h3 = *(const f32x4*)(hp + 3 * Bsz);
#pragma unroll
        for (int r = 0; r < 8; ++r) {
            const f32x4 wv = *(const f32x4*)(w + r * Hn + k);
            fma4v(acc[r], h0, wv.x); fma4v(acc[r], h1, wv.y);
            fma4v(acc[r], h2, wv.z); fma4v(acc[r], h3, wv.w);
        }
    }
}

__global__ __launch_bounds__(NTHR, 1)
void lstm_seq(const float* __restrict__ iput,   // [B][T]
              const float* __restrict__ Wih0,   // [2048]
              const float* __restrict__ Wih,    // [3][2048][512]
              const float* __restrict__ Whh,    // [4][2048][512]
              const float* __restrict__ bih,    // [4][2048]
              const float* __restrict__ bhh,    // [4][2048]
              const float* __restrict__ Wlin,   // [512]
              const float* __restrict__ blin,   // [1]
              float* __restrict__ out,          // [B][320]
              uint32_t* __restrict__ wsb)       // barrier state (zeroed)
{
    extern __shared__ float sm[];
    const int bi  = blockIdx.x;
    const int tid = threadIdx.x;
    uint32_t e = 0;

    const uint32_t x = xcc_id();
    uint32_t cnt_x = 0;
    if (tid == 0) rmw_add(wsb + WS_BCOUNT + x, 1u);   // discovery

    // ---- stage weights into LDS (row r=(jl<<2)|q -> gate row q*512+bi*2+jl)
    for (int i = tid; i < Ln * 8 * Hn; i += NTHR) {
        const int lyr = i >> 12, rem = i & 4095, r = rem >> 9, k = rem & 511;
        sm[OFF_WHH + i] = Whh[((size_t)(lyr * Gn + (r & 3) * Hn + bi * 2 + (r >> 2))) * Hn + k];
    }
    for (int i = tid; i < (Ln - 1) * 8 * Hn; i += NTHR) {
        const int lyr = i >> 12, rem = i & 4095, r = rem >> 9, k = rem & 511;
        sm[OFF_WIH + i] = Wih[((size_t)(lyr * Gn + (r & 3) * Hn + bi * 2 + (r >> 2))) * Hn + k];
    }
    if (tid < Ln * 8) {
        const int lyr = tid >> 3, r = tid & 7;
        const int gg = lyr * Gn + (r & 3) * Hn + bi * 2 + (r >> 2);
        sm[OFF_BS + tid] = bih[gg] + bhh[gg];
    }
    if (tid < 8) sm[OFF_W0 + tid] = Wih0[(tid & 3) * Hn + bi * 2 + (tid >> 2)];
    for (int i = tid; i < Hn; i += NTHR) sm[OFF_WLIN + i] = Wlin[i];
    for (int i = tid; i < Ln * 2 * Bsz; i += NTHR) sm[OFF_C + i] = 0.0f;

    // zero persistent h (write-through; boot_bar release covers either way)
    for (int i = bi * NTHR + tid; i < 2 * LHB; i += NBLK * NTHR)
        GSTF(&g_h[i], 0.0f);

    const float blin0 = blin[0];
    boot_bar(wsb, tid);
    if (tid == 0) cnt_x = ald(wsb + WS_BCOUNT + x);   // final per-XCD count

    // ============ warmup: diagonal wavefront, 1 barrier per phase ============
    // phase s: layer l computes t = s - l (active iff 0 <= t < 256).
    {
        const int l   = tid >> 7;        // this thread's layer 0..3
        const int sub = tid & 127;
        const int bgw = sub & 15, b4w = bgw * 4;
        const int kgw = sub >> 4;        // 0..7, k-chunk of 64
        const int k0w = kgw * 64;
        const int w2  = (tid >> 6) & 1;  // wave-within-layer

        for (int s = 0; s < NPH_W; ++s) {
            const int pp = s & 1;
            float* cur        = g_h + pp * LHB;
            const float* prev = g_h + (pp ^ 1) * LHB;
            const int t = s - l;
            const bool act = ((unsigned)t < (unsigned)Tn);

            f32x4 acc[8];
#pragma unroll
            for (int r = 0; r < 8; ++r) acc[r] = (f32x4){0.f, 0.f, 0.f, 0.f};

            if (act) {
                {   // hidden-hidden: h_l(t-1) = prev[l]
                    const float* wh  = sm + OFF_WHH + l * 8 * Hn;
                    const float* hp0 = prev + (size_t)l * HB;
#pragma unroll 4
                    for (int c = 0; c < 16; ++c) {
                        const int k = k0w + (((c + (kgw & 3) * 4) & 15) << 2);
                        const float* hp = hp0 + (size_t)k * Bsz + b4w;
                        const f32x4 h0 = *(const f32x4*)(hp);
                        const f32x4 h1 = *(const f32x4*)(hp + Bsz);
                        const f32x4 h2 = *(const f32x4*)(hp + 2 * Bsz);
                        const f32x4 h3 = *(const f32x4*)(hp + 3 * Bsz);
#pragma unroll
                        for (int r = 0; r < 8; ++r) {
                            const f32x4 wv = *(const f32x4*)(wh + r * Hn + k);
                            fma4v(acc[r], h0, wv.x); fma4v(acc[r], h1, wv.y);
                            fma4v(acc[r], h2, wv.z); fma4v(acc[r], h3, wv.w);
                        }
                    }
                }
                if (l > 0) {   // input: h_{l-1}(t) = prev[l-1]
                    const float* wh  = sm + OFF_WIH + (l - 1) * 8 * Hn;
                    const float* hp0 = prev + (size_t)(l - 1) * HB;
#pragma unroll 4
                    for (int c = 0; c < 16; ++c) {
                        const int k = k0w + (((c + (kgw & 3) * 4) & 15) << 2);
                        const float* hp = hp0 + (size_t)k * Bsz + b4w;
                        const f32x4 h0 = *(const f32x4*)(hp);
                        const f32x4 h1 = *(const f32x4*)(hp + Bsz);
                        const f32x4 h2 = *(const f32x4*)(hp + 2 * Bsz);
                        const f32x4 h3 = *(const f32x4*)(hp + 3 * Bsz);
#pragma unroll
                        for (int r = 0; r < 8; ++r) {
                            const f32x4 wv = *(const f32x4*)(wh + r * Hn + k);
                            fma4v(acc[r], h0, wv.x); fma4v(acc[r], h1, wv.y);
                            fma4v(acc[r], h2, wv.z); fma4v(acc[r], h3, wv.w);
                        }
                    }
                }
            }

            // in-wave reduce over the wave's 4 kg-chunks (lanes xor 16, 32)
#pragma unroll
            for (int r = 0; r < 8; ++r) {
                f32x4 a = acc[r];
                a.x += __shfl_xor(a.x, 16); a.y += __shfl_xor(a.y, 16);
                a.z += __shfl_xor(a.z, 16); a.w += __shfl_xor(a.w, 16);
                a.x += __shfl_xor(a.x, 32); a.y += __shfl_xor(a.y, 32);
                a.z += __shfl_xor(a.z, 32); a.w += __shfl_xor(a.w, 32);
                acc[r] = a;
            }
            if ((tid & 48) == 0) {
#pragma unroll
                for (int r = 0; r < 8; ++r)
                    *(f32x4*)&sm[OFF_PART + ((l * 2 + w2) * 8 + r) * Bsz + b4w] = acc[r];
            }
            __syncthreads();

            // stage A: 2048 gate values (4 per thread)
#pragma unroll
            for (int it = 0; it < 4; ++it) {
                const int idx = it * NTHR + tid;
                const int la = idx >> 9, r = (idx >> 6) & 7, b = idx & 63;
                float v = sm[OFF_BS + la * 8 + r]
                        + sm[OFF_PART + ((la * 2 + 0) * 8 + r) * Bsz + b]
                        + sm[OFF_PART + ((la * 2 + 1) * 8 + r) * Bsz + b];
                if (la == 0 && s < Tn)
                    v = fmaf(iput[b * Tn + s], sm[OFF_W0 + r], v);
                sm[OFF_GSUM + idx] = v;
            }
            __syncthreads();

            // stage B: one cell element per thread (4 layers x 2 cols x 64 b)
            {
                const int lb = tid >> 7, jl = (tid >> 6) & 1, b = tid & 63;
                const int tb = s - lb;
                if ((unsigned)tb < (unsigned)Tn) {
                    const int jg = bi * 2 + jl;
                    const float* gs = sm + OFF_GSUM + lb * 512 + (jl << 2) * 64;
                    const float i_ = sigm(gs[0 * 64 + b]);
                    const float f_ = sigm(gs[1 * 64 + b]);
                    const float g_ = tanhf(gs[2 * 64 + b]);
                    const float o_ = sigm(gs[3 * 64 + b]);
                    float* cp = sm + OFF_C + (lb * 2 + jl) * Bsz + b;
                    const float c2 = fmaf(f_, *cp, i_ * g_);
                    *cp = c2;
                    const float h2 = o_ * tanhf(c2);
                    GSTF(&cur[((size_t)lb * Hn + jg) * Bsz + b], h2);
                    if (lb == 3)
                        GSTF(&g_hist[((size_t)tb * Hn + jg) * Bsz + b], h2);
                }
            }
            gbar(wsb, tid, x, cnt_x, e);
        }
    }

    // ============ batched readout of out[:,0..255] + parity consolidation ====
    {
        const int b = tid & 63, jq = tid >> 6;
        const float* hp = g_hist + ((size_t)bi * Hn + jq * 64) * Bsz + b;
        const float* wp = sm + OFF_WLIN + jq * 64;
        float r = 0.0f;
#pragma unroll 8
        for (int j = 0; j < 64; ++j) r = fmaf(hp[j * Bsz], wp[j], r);
        sm[OFF_RP + jq * Bsz + b] = r;
        // copy h_l(255) for l=1,3 from parity-0 buffer into parity-1 buffer
        if (tid < 256) {
            const int li = (tid >> 7) * 2 + 1;          // 1 or 3
            const int jl = (tid >> 6) & 1, bb = tid & 63;
            const size_t o = ((size_t)li * Hn + bi * 2 + jl) * Bsz + bb;
            const float v = g_h[o];
            GSTF(&g_h[LHB + o], v);
        }
        __syncthreads();
        if (tid < Bsz) {
            float xx = blin0;
#pragma unroll
            for (int q = 0; q < 8; ++q) xx += sm[OFF_RP + q * Bsz + tid];
            out[tid * TTn + bi] = xx;
            if (bi == 255) GSTF(&g_xsg[tid], xx);
        }
        gbar(wsb, tid, x, cnt_x, e);
    }

    // ============ future phase: serial 4-layer chain + folded readout =======
    {
        const int bg  = tid & 15, b4 = bg * 4;
        const int kg  = tid >> 4;        // 0..31, chunk of 16 k
        const int k0  = kg * 16;
        const int wv_ = tid >> 6;

        for (int t = Tn; t < TTn; ++t) {
            const int ci = t & 1;
            float* hcur        = g_h + ci * LHB;
            const float* hprev = g_h + (ci ^ 1) * LHB;

            for (int lyr = 0; lyr < Ln; ++lyr) {
                // x for this t: wave 0 sums distributed partials (overlaps GEMM)
                if (lyr == 0 && tid < Bsz) {
                    float xx;
                    if (t == Tn) {
                        xx = g_xsg[tid];
                    } else {
                        const f32x4* pp2 = (const f32x4*)(g_p + tid * NBLK);
                        f32x4 s4 = {0.f, 0.f, 0.f, 0.f};
#pragma unroll 16
                        for (int q = 0; q < NBLK / 4; ++q) s4 += pp2[q];
                        xx = s4.x + s4.y + s4.z + s4.w + blin0;
                        if (bi == ((t - 1) & 255))
                            out[tid * TTn + (t - 1)] = xx;
                    }
                    sm[OFF_XS + tid] = xx;
                }

                f32x4 acc[8];
#pragma unroll
                for (int r = 0; r < 8; ++r) acc[r] = (f32x4){0.f, 0.f, 0.f, 0.f};

                if (lyr > 0)
                    gemm16(sm + OFF_WIH + (lyr - 1) * 8 * Hn,
                           hcur + (size_t)(lyr - 1) * HB, k0, b4, acc);
                gemm16(sm + OFF_WHH + lyr * 8 * Hn,
                       hprev + (size_t)lyr * HB, k0, b4, acc);

#pragma unroll
                for (int r = 0; r < 8; ++r) {
                    f32x4 a = acc[r];
                    a.x += __shfl_xor(a.x, 16); a.y += __shfl_xor(a.y, 16);
                    a.z += __shfl_xor(a.z, 16); a.w += __shfl_xor(a.w, 16);
                    a.x += __shfl_xor(a.x, 32); a.y += __shfl_xor(a.y, 32);
                    a.z += __shfl_xor(a.z, 32); a.w += __shfl_xor(a.w, 32);
                    acc[r] = a;
                }
                if ((tid & 48) == 0) {
#pragma unroll
                    for (int r = 0; r < 8; ++r)
                        *(f32x4*)&sm[OFF_PART + (wv_ * 8 + r) * Bsz + b4] = acc[r];
                }
                __syncthreads();

                {   // stage A: one gate value per thread
                    const int r = tid >> 6, b = tid & 63;
                    float v = sm[OFF_BS + lyr * 8 + r];
#pragma unroll
                    for (int q = 0; q < 8; ++q)
                        v += sm[OFF_PART + (q * 8 + r) * Bsz + b];
                    if (lyr == 0)
                        v = fmaf(sm[OFF_XS + b], sm[OFF_W0 + r], v);
                    sm[OFF_GSUM + tid] = v;
                }
                __syncthreads();

                // stage B
                float h2 = 0.0f;
                if (tid < 128) {
                    const int jl = tid >> 6, b = tid & 63;
                    const int jg = bi * 2 + jl;
                    const float* gs = sm + OFF_GSUM + jl * 4 * Bsz;
                    const float i_ = sigm(gs[0 * Bsz + b]);
                    const float f_ = sigm(gs[1 * Bsz + b]);
                    const float g_ = tanhf(gs[2 * Bsz + b]);
                    const float o_ = sigm(gs[3 * Bsz + b]);
                    float* cp = sm + OFF_C + (lyr * 2 + jl) * Bsz + b;
                    const float c2 = fmaf(f_, *cp, i_ * g_);
                    *cp = c2;
                    h2 = o_ * tanhf(c2);
                    GSTF(&hcur[((size_t)lyr * Hn + jg) * Bsz + b], h2);
                    if (lyr == 3 && jl == 1)
                        sm[OFF_RP + b] = h2 * sm[OFF_WLIN + jg];
                }
                __syncthreads();
                if (lyr == 3 && tid < Bsz) {
                    const float pv = fmaf(h2, sm[OFF_WLIN + bi * 2], sm[OFF_RP + tid]);
                    GSTF(&g_p[tid * NBLK + bi], pv);
                }

                gbar(wsb, tid, x, cnt_x, e);
            }
        }
    }

    // ---- final readout out[:,319]
    if (bi == 0 && tid < Bsz) {
        const f32x4* pp2 = (const f32x4*)(g_p + tid * NBLK);
        f32x4 s4 = {0.f, 0.f, 0.f, 0.f};
#pragma unroll 16
        for (int q = 0; q < NBLK / 4; ++q) s4 += pp2[q];
        out[tid * TTn + (TTn - 1)] = s4.x + s4.y + s4.z + s4.w + blin0;
    }
}

extern "C" void kernel_launch(void* const* d_in, const int* in_sizes, int n_in,
                              void* d_out, int out_size, void* d_ws, size_t ws_size,
                              hipStream_t stream) {
    const float* iput = (const float*)d_in[0];
    const float* Wih0 = (const float*)d_in[1];
    const float* Wih  = (const float*)d_in[2];
    const float* Whh  = (const float*)d_in[3];
    const float* bih  = (const float*)d_in[4];
    const float* bhh  = (const float*)d_in[5];
    const float* Wlin = (const float*)d_in[6];
    const float* blin = (const float*)d_in[7];
    float* out = (float*)d_out;
    uint32_t* wsb = (uint32_t*)d_ws;

    (void)hipFuncSetAttribute((const void*)lstm_seq,
                              hipFuncAttributeMaxDynamicSharedMemorySize, SMEM_BYTES);

    // zero barrier state each launch (graph-capturable async memset)
    (void)hipMemsetAsync(d_ws, 0, WS_U32S * sizeof(uint32_t), stream);

    void* args[] = {&iput, &Wih0, &Wih, &Whh, &bih, &bhh, &Wlin, &blin, &out, &wsb};
    hipLaunchCooperativeKernel((const void*)lstm_seq, dim3(NBLK), dim3(NTHR), args,
                               SMEM_BYTES, stream);
}